// Round 2
// baseline (773.248 us; speedup 1.0000x reference)
//
#include <hip/hip_runtime.h>
#include <hip/hip_bf16.h>

typedef float  floatx4 __attribute__((ext_vector_type(4)));
typedef short  short8  __attribute__((ext_vector_type(8)));
typedef short  short4v __attribute__((ext_vector_type(4)));

#define NB   32
#define NC   512
#define NHW  3136

// resample map: p//7*6 + min(p%7,5)
__device__ __forceinline__ int ridx(int p) {
    int q = p / 7;
    int r = p - q * 7;
    return q * 6 + (r < 5 ? r : 5);
}
__device__ __forceinline__ short f2bf(float f) {
    unsigned int x = __builtin_bit_cast(unsigned int, f);
    x += 0x7fffu + ((x >> 16) & 1u);           // RNE
    return (short)(x >> 16);
}

// ---- pre-pass: conv_w f32 -> bf16 into ws ----
__global__ __launch_bounds__(256)
void wconv_kernel(const float* __restrict__ w, short* __restrict__ wb)
{
    int id = (blockIdx.x * 256 + threadIdx.x) * 4;   // 65536 threads x 4 = 262144
    float4 v = *(const float4*)(w + id);
    short4v s;
    s[0] = f2bf(v.x); s[1] = f2bf(v.y); s[2] = f2bf(v.z); s[3] = f2bf(v.w);
    *(short4v*)(wb + id) = s;
}

// Tile: M=128 spatial slots (112 real: rows 2ph,2ph+1), N=128 out-ch, BK=64.
// 4 waves in 2x2: wave=(wo,wm) owns 64 o x 64 m, 4x4 frags of 16x16x32 MFMA.
__global__ __launch_bounds__(256, 2)
void fused_bn_conv_pool(const float* __restrict__ x,
                        const float* __restrict__ g_,
                        const float* __restrict__ be_,
                        const float* __restrict__ mn_,
                        const float* __restrict__ vr_,
                        const short* __restrict__ wgt,
                        float* __restrict__ out)
{
    __shared__ char smem[40960];
    float2* pb = (float2*)smem;                 // [1024] scale/shift, 8KB
    short*  Wt = (short*)(smem + 8192);         // [128][64] bf16, 16KB (swizzled 16B chunks)
    short*  At = (short*)(smem + 24576);        // [128][64] bf16, 16KB (swizzled 16B chunks)
    float*  ys = (float*)smem;                  // [32][132] f32 epilogue (overlaps pb/Wt)

    const int t    = threadIdx.x;
    const int bx   = blockIdx.x;
    const int site = bx >> 1;
    const int nt   = bx & 1;                    // o-half: [nt*128, nt*128+128)
    const int b    = site / 28;
    const int ph   = site - b * 28;

    // BN params -> (scale, shift) in LDS
    for (int c = t; c < 1024; c += 256) {
        float sc = g_[c] * rsqrtf(vr_[c] + 1e-5f);
        pb[c] = make_float2(sc, be_[c] - mn_[c] * sc);
    }

    // ---- staging mapping: thread owns 8 consecutive channels (cc) x 4 m (mg) ----
    const int cc     = t & 7;                   // k-octet within BK
    const int mg     = t >> 3;                  // 0..31
    const int m_base = mg * 4;                  // 0..124
    const bool realm = (m_base < 112);
    const int rr = (m_base >= 56) ? 1 : 0;      // row within pair (groups never straddle rows)
    const int w0 = m_base - rr * 56;
    const int hs = 4 + ridx(2 * ph + rr);       // gather source row
    int offu[4];
#pragma unroll
    for (int j = 0; j < 4; ++j) offu[j] = hs * 56 + 4 + ridx(w0 + j);
    const int xb   = b * NC * NHW;
    const int offd = 112 * ph + m_base;         // h*56+w == 112*ph+m (linear!)

    // ---- MFMA mapping ----
    const int lid = t & 63;
    const int wv  = t >> 6;
    const int wo  = wv & 1;
    const int wm  = wv >> 1;
    const int col = lid & 15;
    const int q4  = lid >> 4;
    const int obw = wo * 64;
    const int mbw = wm * 64;
    const int sw  = col & 7;                    // read-side chunk swizzle key

    floatx4 acc[4][4];
#pragma unroll
    for (int i = 0; i < 4; ++i)
#pragma unroll
        for (int j = 0; j < 4; ++j)
            acc[i][j] = (floatx4){0.f, 0.f, 0.f, 0.f};

    const short* wrow = wgt + nt * 128 * 1024;

    __syncthreads();                            // params ready

    for (int kc = 0; kc < 16; ++kc) {
        const int k0 = kc * 64;

        // ---- stage Wt (bf16 from prepass): [o][k], 16B chunks, chunk ^= o&7 ----
#pragma unroll
        for (int it = 0; it < 4; ++it) {
            int qq  = it * 256 + t;
            int o   = qq >> 3, seg = qq & 7;
            *(short8*)(Wt + o * 64 + ((seg ^ (o & 7)) * 8)) =
                *(const short8*)(wrow + o * 1024 + k0 + seg * 8);
        }

        // ---- stage At: BN+ReLU fused, f32 -> bf16, [m][k], chunk ^= m&7 ----
        {
            const int cbase = k0 + cc * 8;
            float2 p[8];
#pragma unroll
            for (int i = 0; i < 8; ++i) p[i] = pb[cbase + i];
            short8 vj[4];
#pragma unroll
            for (int j = 0; j < 4; ++j) vj[j] = (short8){0,0,0,0,0,0,0,0};
            if (realm) {
                if (k0 < 512) {                  // direct half: float4 loads along w
#pragma unroll
                    for (int i = 0; i < 8; ++i) {
                        float4 v = *(const float4*)(x + xb + (cbase + i) * NHW + offd);
                        float vv[4] = {v.x, v.y, v.z, v.w};
#pragma unroll
                        for (int j = 0; j < 4; ++j) {
                            float f = fmaxf(vv[j] * p[i].x + p[i].y, 0.f);
                            vj[j][i] = f2bf(f);
                        }
                    }
                } else {                         // upsampled half: gather (L1/L2-hot)
#pragma unroll
                    for (int i = 0; i < 8; ++i) {
                        const float* cp = x + xb + (cbase + i - 512) * NHW;
#pragma unroll
                        for (int j = 0; j < 4; ++j) {
                            float f = fmaxf(cp[offu[j]] * p[i].x + p[i].y, 0.f);
                            vj[j][i] = f2bf(f);
                        }
                    }
                }
            }
#pragma unroll
            for (int j = 0; j < 4; ++j) {
                int m = m_base + j;
                *(short8*)(At + m * 64 + ((cc ^ (m & 7)) * 8)) = vj[j];
            }
        }
        __syncthreads();

        // ---- MFMA: D[o][m] += Wt * At ----
#pragma unroll
        for (int ks = 0; ks < 2; ++ks) {
            const int cb = ks * 4 + q4;          // 16B chunk index of this lane's k-slice
            short8 af[4], bf[4];
#pragma unroll
            for (int of = 0; of < 4; ++of) {
                int row = obw + of * 16 + col;
                af[of] = *(const short8*)(Wt + row * 64 + ((cb ^ sw) * 8));
            }
#pragma unroll
            for (int mf = 0; mf < 4; ++mf) {
                int row = mbw + mf * 16 + col;
                bf[mf] = *(const short8*)(At + row * 64 + ((cb ^ sw) * 8));
            }
#pragma unroll
            for (int of = 0; of < 4; ++of)
#pragma unroll
                for (int mf = 0; mf < 4; ++mf)
                    acc[of][mf] = __builtin_amdgcn_mfma_f32_16x16x32_bf16(
                        af[of], bf[mf], acc[of][mf], 0, 0, 0);
        }
        __syncthreads();
    }

    // ---- epilogue: 4 slices of 32 o; acc -> LDS f32 -> 2x2 pool -> f32 out ----
#pragma unroll 1
    for (int s = 0; s < 4; ++s) {
        if (wo == (s >> 1)) {
#pragma unroll
            for (int of2 = 0; of2 < 2; ++of2) {
                const int of  = (s & 1) * 2 + of2;
                const int olb = of2 * 16 + q4 * 4;   // o within slice (row = q*4+reg)
#pragma unroll
                for (int mf = 0; mf < 4; ++mf) {
                    const int m = mbw + mf * 16 + col;
#pragma unroll
                    for (int rg = 0; rg < 4; ++rg)
                        ys[(olb + rg) * 132 + m] = acc[of][mf][rg];
                }
            }
        }
        __syncthreads();
        for (int i = t; i < 896; i += 256) {
            int ol = i / 28;
            int pw = i - ol * 28;
            const float* yr = ys + ol * 132 + 2 * pw;
            float v = (yr[0] + yr[1] + yr[56] + yr[57]) * 0.25f;
            int og = nt * 128 + s * 32 + ol;
            out[((b * 256 + og) * 28 + ph) * 28 + pw] = v;
        }
        __syncthreads();
    }
}

extern "C" void kernel_launch(void* const* d_in, const int* in_sizes, int n_in,
                              void* d_out, int out_size, void* d_ws, size_t ws_size,
                              hipStream_t stream) {
    (void)in_sizes; (void)n_in; (void)out_size; (void)ws_size;
    const float* x  = (const float*)d_in[0];
    const float* g  = (const float*)d_in[1];
    const float* be = (const float*)d_in[2];
    const float* mn = (const float*)d_in[3];
    const float* vr = (const float*)d_in[4];
    const float* w  = (const float*)d_in[5];
    float* o  = (float*)d_out;
    short* wb = (short*)d_ws;                    // 256*1024 bf16 = 512 KB scratch

    wconv_kernel<<<dim3(256), dim3(256), 0, stream>>>(w, wb);
    fused_bn_conv_pool<<<dim3(32 * 28 * 2), dim3(256), 0, stream>>>(x, g, be, mn, vr, wb, o);
}

// Round 3
// 456.736 us; speedup vs baseline: 1.6930x; 1.6930x over previous
//
#include <hip/hip_runtime.h>
#include <hip/hip_bf16.h>

typedef float  floatx4 __attribute__((ext_vector_type(4)));
typedef short  short8  __attribute__((ext_vector_type(8)));
typedef short  short4v __attribute__((ext_vector_type(4)));

#define NB   32
#define NC   512
#define NHW  3136

// resample map: p//7*6 + min(p%7,5)
__device__ __forceinline__ int ridx(int p) {
    int q = p / 7;
    int r = p - q * 7;
    return q * 6 + (r < 5 ? r : 5);
}
__device__ __forceinline__ short f2bf(float f) {
    unsigned int x = __builtin_bit_cast(unsigned int, f);
    x += 0x7fffu + ((x >> 16) & 1u);           // RNE
    return (short)(x >> 16);
}

// ---- pre-pass: conv_w f32 -> bf16 into ws ----
__global__ __launch_bounds__(256)
void wconv_kernel(const float* __restrict__ w, short* __restrict__ wb)
{
    int id = (blockIdx.x * 256 + threadIdx.x) * 4;   // 65536 threads x 4 = 262144
    float4 v = *(const float4*)(w + id);
    short4v s;
    s[0] = f2bf(v.x); s[1] = f2bf(v.y); s[2] = f2bf(v.z); s[3] = f2bf(v.w);
    *(short4v*)(wb + id) = s;
}

// Tile: M=128 spatial slots (112 real: rows 2ph,2ph+1), N=128 out-ch, BK=64.
// 4 waves in 2x2: wave=(wo,wm) owns 64 o x 64 m, 4x4 frags of 16x16x32 MFMA.
__global__ __launch_bounds__(256, 2)
void fused_bn_conv_pool(const float* __restrict__ x,
                        const float* __restrict__ g_,
                        const float* __restrict__ be_,
                        const float* __restrict__ mn_,
                        const float* __restrict__ vr_,
                        const short* __restrict__ wgt,
                        float* __restrict__ out)
{
    __shared__ char smem[40960];
    float2* pb = (float2*)smem;                 // [1024] scale/shift, 8KB
    short*  Wt = (short*)(smem + 8192);         // [128][64] bf16, 16KB (swizzled 16B chunks)
    short*  At = (short*)(smem + 24576);        // [128][64] bf16, 16KB (swizzled 16B chunks)
    float*  ys = (float*)smem;                  // [32][132] f32 epilogue (overlaps pb/Wt)

    const int t    = threadIdx.x;
    const int bx   = blockIdx.x;
    const int site = bx >> 1;
    const int nt   = bx & 1;                    // o-half: [nt*128, nt*128+128)
    const int b    = site / 28;
    const int ph   = site - b * 28;

    // BN params -> (scale, shift) in LDS
    for (int c = t; c < 1024; c += 256) {
        float sc = g_[c] * rsqrtf(vr_[c] + 1e-5f);
        pb[c] = make_float2(sc, be_[c] - mn_[c] * sc);
    }

    // ---- staging mapping: thread owns 8 consecutive channels (cc) x 4 m (mg) ----
    const int cc     = t & 7;                   // k-octet within BK
    const int mg     = t >> 3;                  // 0..31
    const int m_base = mg * 4;                  // 0..124
    const bool realm = (m_base < 112);
    const int rr = (m_base >= 56) ? 1 : 0;      // row within pair (groups never straddle rows)
    const int w0 = m_base - rr * 56;
    const int hs = 4 + ridx(2 * ph + rr);       // gather source row
    int offu[4];
#pragma unroll
    for (int j = 0; j < 4; ++j) offu[j] = hs * 56 + 4 + ridx(w0 + j);
    const int xb   = b * NC * NHW;
    const int offd = 112 * ph + m_base;         // h*56+w == 112*ph+m (linear!)

    // ---- MFMA mapping ----
    const int lid = t & 63;
    const int wv  = t >> 6;
    const int wo  = wv & 1;
    const int wm  = wv >> 1;
    const int col = lid & 15;
    const int q4  = lid >> 4;
    const int obw = wo * 64;
    const int mbw = wm * 64;
    const int sw  = col & 7;                    // read-side chunk swizzle key

    floatx4 acc[4][4];
#pragma unroll
    for (int i = 0; i < 4; ++i)
#pragma unroll
        for (int j = 0; j < 4; ++j)
            acc[i][j] = (floatx4){0.f, 0.f, 0.f, 0.f};

    const short* wrow = wgt + nt * 128 * 1024;

    __syncthreads();                            // params ready

    for (int kc = 0; kc < 16; ++kc) {
        const int k0 = kc * 64;

        // ---- stage Wt (bf16 from prepass): [o][k], 16B chunks, chunk ^= o&7 ----
#pragma unroll
        for (int it = 0; it < 4; ++it) {
            int qq  = it * 256 + t;
            int o   = qq >> 3, seg = qq & 7;
            *(short8*)(Wt + o * 64 + ((seg ^ (o & 7)) * 8)) =
                *(const short8*)(wrow + o * 1024 + k0 + seg * 8);
        }

        // ---- stage At: BN+ReLU fused, f32 -> bf16, [m][k], chunk ^= m&7 ----
        {
            const int cbase = k0 + cc * 8;
            float2 p[8];
#pragma unroll
            for (int i = 0; i < 8; ++i) p[i] = pb[cbase + i];
            short8 vj[4];
#pragma unroll
            for (int j = 0; j < 4; ++j) vj[j] = (short8){0,0,0,0,0,0,0,0};
            if (realm) {
                if (k0 < 512) {                  // direct half: float4 loads along w
#pragma unroll
                    for (int i = 0; i < 8; ++i) {
                        float4 v = *(const float4*)(x + xb + (cbase + i) * NHW + offd);
                        float vv[4] = {v.x, v.y, v.z, v.w};
#pragma unroll
                        for (int j = 0; j < 4; ++j) {
                            float f = fmaxf(vv[j] * p[i].x + p[i].y, 0.f);
                            vj[j][i] = f2bf(f);
                        }
                    }
                } else {                         // upsampled half: gather (L1/L2-hot)
#pragma unroll
                    for (int i = 0; i < 8; ++i) {
                        const float* cp = x + xb + (cbase + i - 512) * NHW;
#pragma unroll
                        for (int j = 0; j < 4; ++j) {
                            float f = fmaxf(cp[offu[j]] * p[i].x + p[i].y, 0.f);
                            vj[j][i] = f2bf(f);
                        }
                    }
                }
            }
#pragma unroll
            for (int j = 0; j < 4; ++j) {
                int m = m_base + j;
                *(short8*)(At + m * 64 + ((cc ^ (m & 7)) * 8)) = vj[j];
            }
        }
        __syncthreads();

        // ---- MFMA: D[o][m] += Wt * At ----
#pragma unroll
        for (int ks = 0; ks < 2; ++ks) {
            const int cb = ks * 4 + q4;          // 16B chunk index of this lane's k-slice
            short8 af[4], bf[4];
#pragma unroll
            for (int of = 0; of < 4; ++of) {
                int row = obw + of * 16 + col;
                af[of] = *(const short8*)(Wt + row * 64 + ((cb ^ sw) * 8));
            }
#pragma unroll
            for (int mf = 0; mf < 4; ++mf) {
                int row = mbw + mf * 16 + col;
                bf[mf] = *(const short8*)(At + row * 64 + ((cb ^ sw) * 8));
            }
#pragma unroll
            for (int of = 0; of < 4; ++of)
#pragma unroll
                for (int mf = 0; mf < 4; ++mf)
                    acc[of][mf] = __builtin_amdgcn_mfma_f32_16x16x32_bf16(
                        af[of], bf[mf], acc[of][mf], 0, 0, 0);
        }
        __syncthreads();
    }

    // ---- epilogue: 4 slices of 32 o; acc -> LDS f32 -> 2x2 pool -> f32 out ----
    // FULLY UNROLLED so acc[][] indices stay compile-time constants (keeps the
    // accumulator in registers; R2's `unroll 1` demoted acc to scratch -> 2 GB
    // of HBM writeback).
#pragma unroll
    for (int s = 0; s < 4; ++s) {
        if (wo == (s >> 1)) {
#pragma unroll
            for (int of2 = 0; of2 < 2; ++of2) {
                const int of  = (s & 1) * 2 + of2;
                const int olb = of2 * 16 + q4 * 4;   // o within slice (row = q*4+reg)
#pragma unroll
                for (int mf = 0; mf < 4; ++mf) {
                    const int m = mbw + mf * 16 + col;
#pragma unroll
                    for (int rg = 0; rg < 4; ++rg)
                        ys[(olb + rg) * 132 + m] = acc[of][mf][rg];
                }
            }
        }
        __syncthreads();
        for (int i = t; i < 896; i += 256) {
            int ol = i / 28;
            int pw = i - ol * 28;
            const float* yr = ys + ol * 132 + 2 * pw;
            float v = (yr[0] + yr[1] + yr[56] + yr[57]) * 0.25f;
            int og = nt * 128 + s * 32 + ol;
            out[((b * 256 + og) * 28 + ph) * 28 + pw] = v;
        }
        __syncthreads();
    }
}

extern "C" void kernel_launch(void* const* d_in, const int* in_sizes, int n_in,
                              void* d_out, int out_size, void* d_ws, size_t ws_size,
                              hipStream_t stream) {
    (void)in_sizes; (void)n_in; (void)out_size; (void)ws_size;
    const float* x  = (const float*)d_in[0];
    const float* g  = (const float*)d_in[1];
    const float* be = (const float*)d_in[2];
    const float* mn = (const float*)d_in[3];
    const float* vr = (const float*)d_in[4];
    const float* w  = (const float*)d_in[5];
    float* o  = (float*)d_out;
    short* wb = (short*)d_ws;                    // 256*1024 bf16 = 512 KB scratch

    wconv_kernel<<<dim3(256), dim3(256), 0, stream>>>(w, wb);
    fused_bn_conv_pool<<<dim3(32 * 28 * 2), dim3(256), 0, stream>>>(x, g, be, mn, vr, wb, o);
}

// Round 4
// 411.308 us; speedup vs baseline: 1.8800x; 1.1104x over previous
//
#include <hip/hip_runtime.h>
#include <hip/hip_bf16.h>

typedef float  floatx4 __attribute__((ext_vector_type(4)));
typedef float  float4a __attribute__((ext_vector_type(4), aligned(4)));
typedef short  short8  __attribute__((ext_vector_type(8)));
typedef short  short4v __attribute__((ext_vector_type(4)));

#define NB   32
#define NC   512
#define NHW  3136

// resample map: p//7*6 + min(p%7,5)
__device__ __forceinline__ int ridx(int p) {
    int q = p / 7;
    int r = p - q * 7;
    return q * 6 + (r < 5 ? r : 5);
}
__device__ __forceinline__ short f2bf(float f) {
    unsigned int x = __builtin_bit_cast(unsigned int, f);
    x += 0x7fffu + ((x >> 16) & 1u);           // RNE
    return (short)(x >> 16);
}
__device__ __forceinline__ void gload_lds16(const void* g, void* l) {
    __builtin_amdgcn_global_load_lds(
        (const __attribute__((address_space(1))) unsigned int*)g,
        (__attribute__((address_space(3))) unsigned int*)l, 16, 0, 0);
}

// ---- pre-pass: conv_w f32 -> bf16; BN -> folded (scale,shift) f32 pairs ----
__global__ __launch_bounds__(256)
void prep_kernel(const float* __restrict__ w,
                 const float* __restrict__ g_, const float* __restrict__ be_,
                 const float* __restrict__ mn_, const float* __restrict__ vr_,
                 short* __restrict__ wb, float* __restrict__ pbg)
{
    int id = (blockIdx.x * 256 + threadIdx.x) * 4;   // 256 blocks x 256 thr x 4 = 262144
    float4 v = *(const float4*)(w + id);
    short4v s;
    s[0] = f2bf(v.x); s[1] = f2bf(v.y); s[2] = f2bf(v.z); s[3] = f2bf(v.w);
    *(short4v*)(wb + id) = s;
    if (blockIdx.x == 0) {
        for (int c = threadIdx.x; c < 1024; c += 256) {
            float sc = g_[c] * rsqrtf(vr_[c] + 1e-5f);
            pbg[2 * c]     = sc;
            pbg[2 * c + 1] = be_[c] - mn_[c] * sc;
        }
    }
}

// Tile: M=128 spatial slots (112 real: rows 2ph,2ph+1), N=128 out-ch, BK=64.
// Double-buffered LDS, 1 barrier/kc; Wt via async global_load_lds (src-swizzled);
// x prefetched into registers AFTER the barrier (never drained by vmcnt(0)).
__global__ __launch_bounds__(256, 2)
void fused_bn_conv_pool(const float* __restrict__ x,
                        const float* __restrict__ pbg,
                        const short* __restrict__ wgt,
                        float* __restrict__ out)
{
    __shared__ char smem[65536];
    short* WtB[2] = { (short*)(smem),         (short*)(smem + 32768) };
    short* AtB[2] = { (short*)(smem + 16384), (short*)(smem + 49152) };
    float* ys = (float*)smem;                  // [32][132] f32 epilogue (overlaps buf0)

    const int t    = threadIdx.x;
    const int bx   = blockIdx.x;
    const int site = bx >> 1;
    const int nt   = bx & 1;                    // o-half: [nt*128, nt*128+128)
    const int b    = site / 28;
    const int ph   = site - b * 28;

    // ---- staging mapping: thread owns 8 consecutive channels (cc) x 4 m (mg) ----
    const int cc     = t & 7;                   // k-octet within BK
    const int mg     = t >> 3;                  // 0..31
    const int m_base = mg * 4;                  // 0..124
    const bool realm = (m_base < 112);
    const int rr = (m_base >= 56) ? 1 : 0;      // row within pair
    const int w0 = m_base - rr * 56;
    const int hs = 4 + ridx(2 * ph + rr);       // gather source row
    const int c0 = ridx(w0);                    // gather base col (cols c0..c0+3 cover all 4)
    const int offg = hs * 56 + 4 + c0;
    int d_[4];
#pragma unroll
    for (int j = 0; j < 4; ++j) d_[j] = ridx(w0 + j) - c0;   // 0..3
    const int xb   = b * NC * NHW;
    const int offd = 112 * ph + m_base;         // h*56+w == 112*ph+m (linear!)

    // ---- MFMA mapping ----
    const int lid = t & 63;
    const int wv  = t >> 6;
    const int wo  = wv & 1;
    const int wm  = wv >> 1;
    const int col = lid & 15;
    const int q4  = lid >> 4;
    const int obw = wo * 64;
    const int mbw = wm * 64;
    const int sw  = col & 7;                    // read-side chunk swizzle key

    floatx4 acc[4][4];
#pragma unroll
    for (int i = 0; i < 4; ++i)
#pragma unroll
        for (int j = 0; j < 4; ++j)
            acc[i][j] = (floatx4){0.f, 0.f, 0.f, 0.f};

    const short* wrow = wgt + nt * 128 * 1024;

    // ---- prefetch registers ----
    float4a pf[8];      // x data for current kc (raw f32)
    float4  pp[4];      // (scale,shift) pairs for current kc's 8 channels

    auto load_pref = [&](int kc) {
        const int k0  = kc * 64;
        const int cb  = k0 + cc * 8;
#pragma unroll
        for (int ii = 0; ii < 4; ++ii) pp[ii] = *(const float4*)(pbg + cb * 2 + ii * 4);
        if (realm) {
            if (k0 < 512) {
#pragma unroll
                for (int i = 0; i < 8; ++i)
                    pf[i] = *(const float4a*)(x + xb + (cb + i) * NHW + offd);
            } else {
#pragma unroll
                for (int i = 0; i < 8; ++i)
                    pf[i] = *(const float4a*)(x + xb + (cb + i - 512) * NHW + offg);
            }
        }
    };

    load_pref(0);

    auto body = [&](int kc, short* Wt, short* At) {
        const int k0 = kc * 64;
        // ---- async-DMA Wt for this kc (source-side XOR swizzle: slot s holds seg s^(o&7)) ----
#pragma unroll
        for (int it = 0; it < 4; ++it) {
            int q = it * 256 + t;
            int o = q >> 3, s = q & 7;
            gload_lds16(wrow + o * 1024 + k0 + ((s ^ (o & 7)) * 8), Wt + q * 8);
        }
        // ---- transform pf -> bf16 At[m][k], chunk ^= m&7 ----
        {
            const bool upper = (k0 >= 512);
            short8 vj[4];
#pragma unroll
            for (int j = 0; j < 4; ++j) vj[j] = (short8){0,0,0,0,0,0,0,0};
            if (realm) {
#pragma unroll
                for (int i = 0; i < 8; ++i) {
                    const float sc = pp[i >> 1][(i & 1) * 2];
                    const float sh = pp[i >> 1][(i & 1) * 2 + 1];
                    float vv[4];
                    if (!upper) {
#pragma unroll
                        for (int j = 0; j < 4; ++j) vv[j] = pf[i][j];
                    } else {
#pragma unroll
                        for (int j = 0; j < 4; ++j) {
                            int dd = d_[j];
                            float a = (dd >= 2) ? pf[i][2] : pf[i][0];
                            float bq = (dd >= 2) ? pf[i][3] : pf[i][1];
                            vv[j] = (dd & 1) ? bq : a;
                        }
                    }
#pragma unroll
                    for (int j = 0; j < 4; ++j)
                        vj[j][i] = f2bf(fmaxf(vv[j] * sc + sh, 0.f));
                }
            }
#pragma unroll
            for (int j = 0; j < 4; ++j) {
                int m = m_base + j;
                *(short8*)(At + m * 64 + ((cc ^ (m & 7)) * 8)) = vj[j];
            }
        }
        __syncthreads();          // drains Wt DMA; At visible; prev MFMA's buf now free

        // ---- prefetch next kc's x + params (stays in flight across MFMA, no barrier) ----
        if (kc < 15) load_pref(kc + 1);

        // ---- MFMA: D[o][m] += Wt * At ----
#pragma unroll
        for (int ks = 0; ks < 2; ++ks) {
            const int cb = ks * 4 + q4;
            short8 af[4], bf[4];
#pragma unroll
            for (int of = 0; of < 4; ++of) {
                int row = obw + of * 16 + col;
                af[of] = *(const short8*)(Wt + row * 64 + ((cb ^ sw) * 8));
            }
#pragma unroll
            for (int mf = 0; mf < 4; ++mf) {
                int row = mbw + mf * 16 + col;
                bf[mf] = *(const short8*)(At + row * 64 + ((cb ^ sw) * 8));
            }
#pragma unroll
            for (int of = 0; of < 4; ++of)
#pragma unroll
                for (int mf = 0; mf < 4; ++mf)
                    acc[of][mf] = __builtin_amdgcn_mfma_f32_16x16x32_bf16(
                        af[of], bf[mf], acc[of][mf], 0, 0, 0);
        }
        // no second barrier: double-buffered
    };

    for (int kc2 = 0; kc2 < 16; kc2 += 2) {
        body(kc2,     WtB[0], AtB[0]);
        body(kc2 + 1, WtB[1], AtB[1]);
    }

    __syncthreads();   // all waves done with buf1 reads before ys (overlaps buf0) reuse

    // ---- epilogue: 4 slices of 32 o; acc -> LDS f32 -> 2x2 pool -> f32 out ----
    // fully unrolled: acc[][] indices must stay compile-time (R2 lesson: scratch demotion)
#pragma unroll
    for (int s = 0; s < 4; ++s) {
        if (wo == (s >> 1)) {
#pragma unroll
            for (int of2 = 0; of2 < 2; ++of2) {
                const int of  = (s & 1) * 2 + of2;
                const int olb = of2 * 16 + q4 * 4;   // o within slice (row = q*4+reg)
#pragma unroll
                for (int mf = 0; mf < 4; ++mf) {
                    const int m = mbw + mf * 16 + col;
#pragma unroll
                    for (int rg = 0; rg < 4; ++rg)
                        ys[(olb + rg) * 132 + m] = acc[of][mf][rg];
                }
            }
        }
        __syncthreads();
        for (int i = t; i < 896; i += 256) {
            int ol = i / 28;
            int pw = i - ol * 28;
            const float* yr = ys + ol * 132 + 2 * pw;
            float v = (yr[0] + yr[1] + yr[56] + yr[57]) * 0.25f;
            int og = nt * 128 + s * 32 + ol;
            out[((b * 256 + og) * 28 + ph) * 28 + pw] = v;
        }
        __syncthreads();
    }
}

extern "C" void kernel_launch(void* const* d_in, const int* in_sizes, int n_in,
                              void* d_out, int out_size, void* d_ws, size_t ws_size,
                              hipStream_t stream) {
    (void)in_sizes; (void)n_in; (void)out_size; (void)ws_size;
    const float* x  = (const float*)d_in[0];
    const float* g  = (const float*)d_in[1];
    const float* be = (const float*)d_in[2];
    const float* mn = (const float*)d_in[3];
    const float* vr = (const float*)d_in[4];
    const float* w  = (const float*)d_in[5];
    float* o   = (float*)d_out;
    short* wb  = (short*)d_ws;                        // 512 KB bf16 weights
    float* pbg = (float*)((char*)d_ws + 524288);      // 8 KB folded BN params

    prep_kernel<<<dim3(256), dim3(256), 0, stream>>>(w, g, be, mn, vr, wb, pbg);
    fused_bn_conv_pool<<<dim3(32 * 28 * 2), dim3(256), 0, stream>>>(x, pbg, wb, o);
}